// Round 8
// baseline (230.711 us; speedup 1.0000x reference)
//
#include <hip/hip_runtime.h>
#include <hip/hip_bf16.h>
#include <stdint.h>

#define DM  1024
#define SEQ 2048
#define NB  2
#define NH  16
#define DKH 64
#define SCL 0.18033688f  // (1/sqrt(64)) * log2(e)  — softmax in exp2 domain

typedef unsigned short u16;
typedef __attribute__((ext_vector_type(8))) short short8;
typedef __attribute__((ext_vector_type(4))) float f32x4;

#define MFMA(a,b,c) __builtin_amdgcn_mfma_f32_16x16x32_bf16((a),(b),(c),0,0,0)

__device__ __forceinline__ void async_g2l16(const void* g, void* l) {
  __builtin_amdgcn_global_load_lds(
      (const __attribute__((address_space(1))) uint32_t*)g,
      (__attribute__((address_space(3))) uint32_t*)l, 16, 0, 0);
}

__device__ __forceinline__ u16 f2bf(float f) {
  uint32_t u = __builtin_bit_cast(uint32_t, f);
  u += 0x7fffu + ((u >> 16) & 1u);
  return (u16)(u >> 16);
}

// swizzled LDS read over 128B rows (attn tiles): XOR bits 4-6 with row&7
__device__ __forceinline__ short8 lds_sw(const char* base, int row, int cb) {
  return *(const short8*)(base + row * 128 + (cb ^ ((row & 7) << 4)));
}

// ---------------------------------------------------------------------------
// prep: fused {weight transpose+convert | q/k/v f32->bf16 convert | mask scan}
// ---------------------------------------------------------------------------
__global__ __launch_bounds__(256) void prep(
    const float* __restrict__ query, const float* __restrict__ key_,
    const float* __restrict__ value, const int* __restrict__ mask,
    const float* __restrict__ w0, const float* __restrict__ w1,
    const float* __restrict__ w2, const float* __restrict__ w3,
    u16* __restrict__ xin, u16* __restrict__ wt_qkv, u16* __restrict__ wt_o,
    int* __restrict__ idx, int* __restrict__ nkv) {
  __shared__ char shm[8320];
  const int bid = blockIdx.x;
  const int t = threadIdx.x;

  if (bid < 1024) {  // ---- weight transpose: Wt[n][k] = bf16(W[k][n]) ----
    u16 (*tile)[65] = (u16(*)[65])shm;
    const int z = bid >> 8, rem = bid & 255;
    const float* W = (z == 0) ? w0 : (z == 1) ? w1 : (z == 2) ? w2 : w3;
    u16* O = (z < 3) ? (wt_qkv + (size_t)z * DM * DM) : wt_o;
    const int k0 = (rem & 15) * 64, n0 = (rem >> 4) * 64;
    const int r = t >> 2, cg = (t & 3) * 16;
    const float* src = W + (size_t)(k0 + r) * DM + n0 + cg;
#pragma unroll
    for (int j = 0; j < 4; ++j) {
      const float4 a = ((const float4*)src)[j];
      tile[r][cg + j * 4 + 0] = f2bf(a.x);
      tile[r][cg + j * 4 + 1] = f2bf(a.y);
      tile[r][cg + j * 4 + 2] = f2bf(a.z);
      tile[r][cg + j * 4 + 3] = f2bf(a.w);
    }
    __syncthreads();
    u16 u[16] __attribute__((aligned(16)));
#pragma unroll
    for (int j = 0; j < 16; ++j) u[j] = tile[cg + j][r];
    u16* dst = O + (size_t)(n0 + r) * DM + k0 + cg;
    *(uint4*)&dst[0] = *(uint4*)&u[0];
    *(uint4*)&dst[8] = *(uint4*)&u[8];
  } else if (bid < 7168) {  // ---- f32 -> bf16 convert ----
    const int cb = bid - 1024;
    const int z = cb >> 11;
    const float* A = (z == 0) ? query : (z == 1) ? key_ : value;
    u16* O = xin + (size_t)z * NB * SEQ * DM;
    const size_t i = (size_t)(cb & 2047) * 256 + t;
    const float4 a = ((const float4*)A)[i * 2];
    const float4 b = ((const float4*)A)[i * 2 + 1];
    u16 v[8] __attribute__((aligned(16)));
    v[0] = f2bf(a.x); v[1] = f2bf(a.y); v[2] = f2bf(a.z); v[3] = f2bf(a.w);
    v[4] = f2bf(b.x); v[5] = f2bf(b.y); v[6] = f2bf(b.z); v[7] = f2bf(b.w);
    *(uint4*)(O + i * 8) = *(uint4*)v;
  } else {  // ---- mask compaction scan ----
    int* cnt = (int*)shm;
    const int b = bid - 7168;
    const int* mp = mask + b * SEQ + t * 8;
    int m[8], c = 0;
#pragma unroll
    for (int j = 0; j < 8; ++j) { m[j] = mp[j]; c += (m[j] == 0); }
    cnt[t] = c;
    __syncthreads();
    for (int off = 1; off < 256; off <<= 1) {
      int v = 0;
      if (t >= off) v = cnt[t - off];
      __syncthreads();
      if (t >= off) cnt[t] += v;
      __syncthreads();
    }
    int base = cnt[t] - c;
    int* ip = idx + b * SEQ;
#pragma unroll
    for (int j = 0; j < 8; ++j)
      if (m[j] == 0) ip[base++] = t * 8 + j;
    const int total = cnt[255];
    if (t == 0) nkv[b] = total;
    for (int p = total + t; p < SEQ; p += 256) ip[p] = 0;
  }
}

// ---------------------------------------------------------------------------
// kvprep: fused {V gather-transpose (1024 blocks) | K gather (512 blocks)}.
// ---------------------------------------------------------------------------
__global__ __launch_bounds__(256) void kvprep(
    const u16* __restrict__ Kin, const u16* __restrict__ Vin,
    const int* __restrict__ idx, u16* __restrict__ Kc, u16* __restrict__ Vt) {
  const int bid = blockIdx.x;
  const int t = threadIdx.x;
  if (bid < 1024) {
    __shared__ u16 tile[64][65];
    const int posT = bid & 31, dmT = (bid >> 5) & 15, b = bid >> 9;
    const int r = t >> 2, cg = (t & 3) * 16;
    const int srow = idx[b * SEQ + posT * 64 + r];
    const u16* src = Vin + ((size_t)b * SEQ + srow) * DM + dmT * 64 + cg;
    u16 v[16] __attribute__((aligned(16)));
    *(uint4*)&v[0] = *(const uint4*)src;
    *(uint4*)&v[8] = *(const uint4*)(src + 8);
#pragma unroll
    for (int j = 0; j < 16; ++j) tile[r][cg + j] = v[j];
    __syncthreads();
    u16 u[16] __attribute__((aligned(16)));
#pragma unroll
    for (int j = 0; j < 16; ++j) u[j] = tile[cg + j][r];
    u16* dst = Vt + ((size_t)b * DM + dmT * 64 + r) * SEQ + posT * 64 + cg;
    *(uint4*)&dst[0] = *(uint4*)&u[0];
    *(uint4*)&dst[8] = *(uint4*)&u[8];
  } else {  // K gather: Kc[b][p][:] = Kin[b][idx[p]][:], 512 blocks x 8 rows
    const int kb = bid - 1024;          // 0..511
    const int b = kb >> 8, rg = kb & 255;
    const int r = rg * 8 + (t >> 5);
    const int srow = idx[b * SEQ + r];
    const int co = (t & 31) * 4;        // uint4 index within the 2KB row
    const uint4* src = (const uint4*)(Kin + ((size_t)b * SEQ + srow) * DM);
    uint4* dst = (uint4*)(Kc + ((size_t)b * SEQ + r) * DM);
#pragma unroll
    for (int j = 0; j < 4; ++j) dst[co + j] = src[co + j];
  }
}

// ---------------------------------------------------------------------------
// GEMM v3: C[M][N] = A[M][K] @ Bt[N][K]^T, bf16 in, f32 accum. 128x128, BK=32.
// Triple-buffered, 2-deep prefetch, counted vmcnt(4) + raw s_barrier (T3/T4).
// LDS row-pair swizzled layout: phys(r,kb)=(r>>1)*128+(((r&1)*64+kb)^((r>>1&7)<<4))
// staged linear-dest with inverse-permuted global sources (rule #21).
// ---------------------------------------------------------------------------
template <int OUT_F32>
__device__ __forceinline__ void gemm128_body(
    const u16* __restrict__ A, const u16* __restrict__ Bt, void* __restrict__ Cv,
    int M, int N, int K, int bx, int by) {
  __shared__ uint4 gbuf[49152 / 16];
  char* lds = (char*)gbuf;
  char* ab[3] = {lds, lds + 8192, lds + 16384};
  char* bb[3] = {lds + 24576, lds + 32768, lds + 40960};

  const int m0 = by * 128, n0 = bx * 128;
  const int t = threadIdx.x, w = t >> 6, l = t & 63;
  const int wr = w >> 1, wc = w & 1;
  const int frow = l & 15, fk8 = (l >> 4) * 8;
  f32x4 acc[4][4] = {};

  // staging inverse map: dest chunk i at P=(w*2+i)*1024 + l*16 holds (ra, ka)
  int ra[2], ka[2];
#pragma unroll
  for (int i = 0; i < 2; ++i) {
    const int P = (w * 2 + i) * 1024 + l * 16;
    const int prow = P >> 7;
    const int un = (P & 127) ^ ((prow & 7) << 4);
    ra[i] = prow * 2 + (un >> 6);
    ka[i] = un & 63;   // byte offset within the 64B logical row
  }
  // read-side physical offsets (tile-invariant)
  int aoff[4], boff[4];
#pragma unroll
  for (int mi = 0; mi < 4; ++mi) {
    const int r = wr * 64 + mi * 16 + frow;
    aoff[mi] = (r >> 1) * 128 + ((((r & 1) << 6) + fk8 * 2) ^ (((r >> 1) & 7) << 4));
  }
#pragma unroll
  for (int ni = 0; ni < 4; ++ni) {
    const int r = wc * 64 + ni * 16 + frow;
    boff[ni] = (r >> 1) * 128 + ((((r & 1) << 6) + fk8 * 2) ^ (((r >> 1) & 7) << 4));
  }

#define GSTAGE(slot, k0)                                                       \
  do {                                                                         \
    _Pragma("unroll")                                                          \
    for (int i = 0; i < 2; ++i) {                                              \
      async_g2l16((const char*)(A + (size_t)(m0 + ra[i]) * K + (k0)) + ka[i],  \
                  ab[slot] + (w * 2 + i) * 1024);                              \
      async_g2l16((const char*)(Bt + (size_t)(n0 + ra[i]) * K + (k0)) + ka[i], \
                  bb[slot] + (w * 2 + i) * 1024);                              \
    }                                                                          \
  } while (0)

  const int nks = K >> 5;   // BK=32
  GSTAGE(0, 0);
  GSTAGE(1, 32);

  int s0 = 0, s1 = 1, s2 = 2;
  for (int ks = 0; ks < nks; ++ks) {
    if (ks + 1 < nks) { asm volatile("s_waitcnt vmcnt(4)" ::: "memory"); }
    else              { asm volatile("s_waitcnt vmcnt(0)" ::: "memory"); }
    __builtin_amdgcn_s_barrier();
    __builtin_amdgcn_sched_barrier(0);
    if (ks + 2 < nks) GSTAGE(s2, (ks + 2) * 32);

    short8 af[4], bf[4];
#pragma unroll
    for (int mi = 0; mi < 4; ++mi) af[mi] = *(const short8*)(ab[s0] + aoff[mi]);
#pragma unroll
    for (int ni = 0; ni < 4; ++ni) bf[ni] = *(const short8*)(bb[s0] + boff[ni]);
    __builtin_amdgcn_s_setprio(1);
#pragma unroll
    for (int mi = 0; mi < 4; ++mi)
#pragma unroll
      for (int ni = 0; ni < 4; ++ni)
        acc[mi][ni] = MFMA(af[mi], bf[ni], acc[mi][ni]);
    __builtin_amdgcn_s_setprio(0);

    const int tmp = s0; s0 = s1; s1 = s2; s2 = tmp;
  }
#undef GSTAGE

  const int crb = (l >> 4) * 4;
  for (int mi = 0; mi < 4; ++mi)
    for (int ni = 0; ni < 4; ++ni)
#pragma unroll
      for (int r = 0; r < 4; ++r) {
        const int row = m0 + wr * 64 + mi * 16 + crb + r;
        const int col = n0 + wc * 64 + ni * 16 + frow;
        if (OUT_F32) ((float*)Cv)[(size_t)row * N + col] = acc[mi][ni][r];
        else         ((u16*)Cv)[(size_t)row * N + col] = f2bf(acc[mi][ni][r]);
      }
}

// XCD-aware bijective swizzle for 256-block (8x32) grids
__device__ __forceinline__ void swz256(int& bx, int& by) {
  const int lin = by * 8 + bx;
  const int s = (lin & 7) * 32 + (lin >> 3);
  bx = s & 7; by = s >> 3;
}

__global__ __launch_bounds__(256) void gemm_qkv(
    const u16* __restrict__ xin, const u16* __restrict__ wt, u16* __restrict__ out) {
  const int z = blockIdx.z;
  int bx = blockIdx.x, by = blockIdx.y;
  swz256(bx, by);
  gemm128_body<0>(xin + (size_t)z * NB * SEQ * DM, wt + (size_t)z * DM * DM,
                  out + (size_t)z * NB * SEQ * DM,
                  NB * SEQ, DM, DM, bx, by);
}

__global__ __launch_bounds__(256) void gemm_out(
    const u16* __restrict__ A, const u16* __restrict__ Bt, float* __restrict__ C) {
  int bx = blockIdx.x, by = blockIdx.y;
  swz256(bx, by);
  gemm128_body<1>(A, Bt, C, NB * SEQ, DM, DM, bx, by);
}

// ---------------------------------------------------------------------------
// Flash attention v4 (unchanged from round 6/7).
// ---------------------------------------------------------------------------
__global__ __launch_bounds__(512) void attn(
    const u16* __restrict__ Q, const u16* __restrict__ Kc,
    const u16* __restrict__ Vtc, const int* __restrict__ nkv,
    u16* __restrict__ O) {
  __shared__ uint4 ldsv[65536 / 16];
  char* lds = (char*)ldsv;       // [0,24K) K x3 | [24K,48K) V x3 | [48K,64K) P x8

  const int bid = blockIdx.x;
  const int swz = (bid & 7) * 64 + (bid >> 3);   // 512 blocks, bijective
  const int qt = swz & 15, h = (swz >> 4) & 15, b = swz >> 8;
  const int t = threadIdx.x, w = t >> 6, l = t & 63;
  const int frow = l & 15, fk8 = (l >> 4) * 8, crb = (l >> 4) * 4;
  const size_t tok0 = (size_t)b * SEQ;
  const int q0 = qt * 128 + w * 16;
  const int hc = h * DKH;
  char* PW = lds + 49152 + w * 2048;

  const int nk = nkv[b];
  const int nt = (nk + 63) >> 6;

  const int T0 = w * 1024 + l * 16;
  const int r0 = T0 >> 7;
  const int c0 = (T0 & 127) ^ ((r0 & 7) << 4);
  const u16* Kg = Kc + tok0 * DM + hc;
  const u16* Vg = Vtc + ((size_t)b * DM + hc) * SEQ;

  short8 qf[2];
#pragma unroll
  for (int ks = 0; ks < 2; ++ks)
    qf[ks] = *(const short8*)(Q + (tok0 + q0 + frow) * DM + hc + ks * 32 + fk8);

  const short ONE = 0x3F80;
  const short8 ONES = {ONE, ONE, ONE, ONE, ONE, ONE, ONE, ONE};

  f32x4 o[4] = {};
  f32x4 ol = {};
  float negm[4] = {-8.f, -8.f, -8.f, -8.f};

  char* kb0 = lds;          char* kb1 = lds + 8192;   char* kb2 = lds + 16384;
  char* vb0 = lds + 24576;  char* vb1 = lds + 32768;  char* vb2 = lds + 40960;

#define STAGE(tile, kd, vd)                                                    \
  do {                                                                         \
    const int kv_ = (tile) * 64;                                               \
    async_g2l16((const char*)(Kg + (size_t)(kv_ + r0) * DM) + c0, (kd) + w * 1024); \
    async_g2l16((const char*)(Vg + (size_t)r0 * SEQ + kv_) + c0, (vd) + w * 1024);  \
  } while (0)

  if (nt > 0) STAGE(0, kb0, vb0);
  if (nt > 1) STAGE(1, kb1, vb1);

  for (int it = 0; it < nt; ++it) {
    if (it + 1 < nt) { asm volatile("s_waitcnt vmcnt(2)" ::: "memory"); }
    else             { asm volatile("s_waitcnt vmcnt(0)" ::: "memory"); }
    __builtin_amdgcn_s_barrier();
    __builtin_amdgcn_sched_barrier(0);
    if (it + 2 < nt) STAGE(it + 2, kb2, vb2);

    const int kv0 = it * 64;
    const char* Kt = kb0;
    const char* Vt = vb0;

    // ---- QK^T + scale + negm fold ----
    f32x4 s[4];
#pragma unroll
    for (int n = 0; n < 4; ++n) {
      short8 kf0 = lds_sw(Kt, n * 16 + frow, fk8 * 2);
      short8 kf1 = lds_sw(Kt, n * 16 + frow, 64 + fk8 * 2);
      f32x4 a = {};
      a = MFMA(qf[0], kf0, a);
      a = MFMA(qf[1], kf1, a);
      s[n] = a;
    }
#pragma unroll
    for (int n = 0; n < 4; ++n)
#pragma unroll
      for (int r = 0; r < 4; ++r)
        s[n][r] = __builtin_fmaf(s[n][r], SCL, negm[r]);

    // ---- last-tile pad kill ----
    if (it == nt - 1) {
#pragma unroll
      for (int n = 0; n < 4; ++n) {
        const bool valid = (kv0 + n * 16 + frow) < nk;
#pragma unroll
        for (int r = 0; r < 4; ++r)
          s[n][r] = valid ? s[n][r] : -1e30f;
      }
    }

    // ---- defer-max (THR=8) ----
    float lm = fmaxf(fmaxf(fmaxf(s[0][0], s[0][1]), fmaxf(s[0][2], s[0][3])),
                     fmaxf(fmaxf(s[1][0], s[1][1]), fmaxf(s[1][2], s[1][3])));
    lm = fmaxf(lm, fmaxf(fmaxf(s[2][0], s[2][1]), fmaxf(s[2][2], s[2][3])));
    lm = fmaxf(lm, fmaxf(fmaxf(s[3][0], s[3][1]), fmaxf(s[3][2], s[3][3])));
    if (__any(lm > 8.0f)) {
#pragma unroll
      for (int r = 0; r < 4; ++r) {
        float mx = fmaxf(fmaxf(s[0][r], s[1][r]), fmaxf(s[2][r], s[3][r]));
        mx = fmaxf(mx, __shfl_xor(mx, 1));
        mx = fmaxf(mx, __shfl_xor(mx, 2));
        mx = fmaxf(mx, __shfl_xor(mx, 4));
        mx = fmaxf(mx, __shfl_xor(mx, 8));
        const float d = fmaxf(mx, 0.f);
        const float al = exp2f(-d);
        negm[r] -= d;
        ol[r] *= al;
#pragma unroll
        for (int dd = 0; dd < 4; ++dd) o[dd][r] *= al;
#pragma unroll
        for (int n = 0; n < 4; ++n) s[n][r] -= d;
      }
    }

    // ---- exp + truncated bf16 P write (swizzled) ----
#pragma unroll
    for (int n = 0; n < 4; ++n)
#pragma unroll
      for (int r = 0; r < 4; ++r) {
        const float p = exp2f(s[n][r]);
        *(u16*)(PW + (crb + r) * 128 +
                ((n * 32 + frow * 2) ^ (((crb + r) & 7) << 4))) =
            (u16)(__builtin_bit_cast(uint32_t, p) >> 16);
      }
    asm volatile("s_waitcnt lgkmcnt(0)" ::: "memory");
    __builtin_amdgcn_sched_barrier(0);

    // ---- PV + row-sum via ones-MFMA ----
    short8 pa0 = lds_sw(PW, frow, fk8 * 2);
    short8 pa1 = lds_sw(PW, frow, 64 + fk8 * 2);
    ol = MFMA(pa1, ONES, MFMA(pa0, ONES, ol));
#pragma unroll
    for (int d = 0; d < 4; ++d) {
      short8 vf0 = lds_sw(Vt, d * 16 + frow, fk8 * 2);
      short8 vf1 = lds_sw(Vt, d * 16 + frow, 64 + fk8 * 2);
      o[d] = MFMA(pa1, vf1, MFMA(pa0, vf0, o[d]));
    }

    // rotate buffers
    char* tk = kb0; kb0 = kb1; kb1 = kb2; kb2 = tk;
    char* tv = vb0; vb0 = vb1; vb1 = vb2; vb2 = tv;
  }
#undef STAGE

  // ---- epilogue ----
#pragma unroll
  for (int r = 0; r < 4; ++r) {
    const float den = ol[r];
    const float inv = den > 0.f ? 1.f / den : 0.f;
#pragma unroll
    for (int d = 0; d < 4; ++d)
      O[(tok0 + q0 + crb + r) * DM + hc + d * 16 + frow] = f2bf(o[d][r] * inv);
  }
}

// ---------------------------------------------------------------------------
extern "C" void kernel_launch(void* const* d_in, const int* in_sizes, int n_in,
                              void* d_out, int out_size, void* d_ws, size_t ws_size,
                              hipStream_t stream) {
  const float* query = (const float*)d_in[0];
  const float* key_  = (const float*)d_in[1];
  const float* value = (const float*)d_in[2];
  const int* mask    = (const int*)d_in[3];
  const float* wq = (const float*)d_in[4];
  const float* wk = (const float*)d_in[5];
  const float* wv = (const float*)d_in[6];
  const float* wo = (const float*)d_in[7];
  float* out = (float*)d_out;
  char* ws = (char*)d_ws;

  // ws layout (bytes):
  // [0,6M)    Wt_QKV (bf16, transposed)   [6M,8M)  Wt_O
  // [8M,32M)  xin (bf16 q|k|v) — live until gemm_qkv; AFTER that:
  //   [8M,16M)  Vtc   [16M,24M) attn_o   [24M,32M) Kc (compacted K)
  // [32M,56M) Q|K|V projections (bf16)
  // [56M,+16K) idx  [+16K,+8) nkv   (disjoint; r4 lesson)
  u16* wt_qkv = (u16*)(ws);
  u16* wt_o   = (u16*)(ws + (6u << 20));
  u16* xin    = (u16*)(ws + (8u << 20));
  u16* vtc    = (u16*)(ws + (8u << 20));
  u16* attn_o = (u16*)(ws + (16u << 20));
  u16* kc     = (u16*)(ws + (24u << 20));
  u16* qkv    = (u16*)(ws + (32u << 20));
  int* idx    = (int*)(ws + (56u << 20));
  int* nkv    = (int*)(ws + (56u << 20) + 16384);

  prep<<<dim3(7170), 256, 0, stream>>>(
      query, key_, value, mask, wq, wk, wv, wo, xin, wt_qkv, wt_o, idx, nkv);

  gemm_qkv<<<dim3(DM / 128, (NB * SEQ) / 128, 3), 256, 0, stream>>>(
      xin, wt_qkv, qkv);

  kvprep<<<dim3(1536), 256, 0, stream>>>(
      qkv + (size_t)NB * SEQ * DM, qkv + (size_t)2 * NB * SEQ * DM, idx, kc, vtc);

  attn<<<dim3(NB * NH * (SEQ / 128)), 512, 0, stream>>>(
      qkv, kc, vtc, nkv, attn_o);

  gemm_out<<<dim3(DM / 128, (NB * SEQ) / 128), 256, 0, stream>>>(
      attn_o, wt_o, out);
}

// Round 9
// 230.185 us; speedup vs baseline: 1.0023x; 1.0023x over previous
//
#include <hip/hip_runtime.h>
#include <hip/hip_bf16.h>
#include <stdint.h>

#define DM  1024
#define SEQ 2048
#define NB  2
#define NH  16
#define DKH 64
#define SCL 0.18033688f  // (1/sqrt(64)) * log2(e)  — softmax in exp2 domain

typedef unsigned short u16;
typedef __attribute__((ext_vector_type(8))) short short8;
typedef __attribute__((ext_vector_type(4))) float f32x4;

#define MFMA(a,b,c) __builtin_amdgcn_mfma_f32_16x16x32_bf16((a),(b),(c),0,0,0)

__device__ __forceinline__ void async_g2l16(const void* g, void* l) {
  __builtin_amdgcn_global_load_lds(
      (const __attribute__((address_space(1))) uint32_t*)g,
      (__attribute__((address_space(3))) uint32_t*)l, 16, 0, 0);
}

__device__ __forceinline__ u16 f2bf(float f) {
  uint32_t u = __builtin_bit_cast(uint32_t, f);
  u += 0x7fffu + ((u >> 16) & 1u);
  return (u16)(u >> 16);
}

// swizzled LDS read over 128B rows: XOR bits 4-6 with row&7
__device__ __forceinline__ short8 lds_sw(const char* base, int row, int cb) {
  return *(const short8*)(base + row * 128 + (cb ^ ((row & 7) << 4)));
}

// ---------------------------------------------------------------------------
// prep: fused {weight transpose+convert (1024 blocks) | mask scan (2 blocks)}
// (q/k/v conversion now fused into gemm_qkv's A-staging)
// ---------------------------------------------------------------------------
__global__ __launch_bounds__(256) void prep(
    const int* __restrict__ mask,
    const float* __restrict__ w0, const float* __restrict__ w1,
    const float* __restrict__ w2, const float* __restrict__ w3,
    u16* __restrict__ wt_qkv, u16* __restrict__ wt_o,
    int* __restrict__ idx, int* __restrict__ nkv) {
  __shared__ char shm[8320];
  const int bid = blockIdx.x;
  const int t = threadIdx.x;

  if (bid < 1024) {  // ---- weight transpose: Wt[n][k] = bf16(W[k][n]) ----
    u16 (*tile)[65] = (u16(*)[65])shm;
    const int z = bid >> 8, rem = bid & 255;
    const float* W = (z == 0) ? w0 : (z == 1) ? w1 : (z == 2) ? w2 : w3;
    u16* O = (z < 3) ? (wt_qkv + (size_t)z * DM * DM) : wt_o;
    const int k0 = (rem & 15) * 64, n0 = (rem >> 4) * 64;
    const int r = t >> 2, cg = (t & 3) * 16;
    const float* src = W + (size_t)(k0 + r) * DM + n0 + cg;
#pragma unroll
    for (int j = 0; j < 4; ++j) {
      const float4 a = ((const float4*)src)[j];
      tile[r][cg + j * 4 + 0] = f2bf(a.x);
      tile[r][cg + j * 4 + 1] = f2bf(a.y);
      tile[r][cg + j * 4 + 2] = f2bf(a.z);
      tile[r][cg + j * 4 + 3] = f2bf(a.w);
    }
    __syncthreads();
    u16 u[16] __attribute__((aligned(16)));
#pragma unroll
    for (int j = 0; j < 16; ++j) u[j] = tile[cg + j][r];
    u16* dst = O + (size_t)(n0 + r) * DM + k0 + cg;
    *(uint4*)&dst[0] = *(uint4*)&u[0];
    *(uint4*)&dst[8] = *(uint4*)&u[8];
  } else {  // ---- mask compaction scan ----
    int* cnt = (int*)shm;
    const int b = bid - 1024;
    const int* mp = mask + b * SEQ + t * 8;
    int m[8], c = 0;
#pragma unroll
    for (int j = 0; j < 8; ++j) { m[j] = mp[j]; c += (m[j] == 0); }
    cnt[t] = c;
    __syncthreads();
    for (int off = 1; off < 256; off <<= 1) {
      int v = 0;
      if (t >= off) v = cnt[t - off];
      __syncthreads();
      if (t >= off) cnt[t] += v;
      __syncthreads();
    }
    int base = cnt[t] - c;
    int* ip = idx + b * SEQ;
#pragma unroll
    for (int j = 0; j < 8; ++j)
      if (m[j] == 0) ip[base++] = t * 8 + j;
    const int total = cnt[255];
    if (t == 0) nkv[b] = total;
    for (int p = total + t; p < SEQ; p += 256) ip[p] = 0;
  }
}

// ---------------------------------------------------------------------------
// kvprep: fused {V gather-transpose (1024 blocks) | K gather (512 blocks)}.
// ---------------------------------------------------------------------------
__global__ __launch_bounds__(256) void kvprep(
    const u16* __restrict__ Kin, const u16* __restrict__ Vin,
    const int* __restrict__ idx, u16* __restrict__ Kc, u16* __restrict__ Vt) {
  const int bid = blockIdx.x;
  const int t = threadIdx.x;
  if (bid < 1024) {
    __shared__ u16 tile[64][65];
    const int posT = bid & 31, dmT = (bid >> 5) & 15, b = bid >> 9;
    const int r = t >> 2, cg = (t & 3) * 16;
    const int srow = idx[b * SEQ + posT * 64 + r];
    const u16* src = Vin + ((size_t)b * SEQ + srow) * DM + dmT * 64 + cg;
    u16 v[16] __attribute__((aligned(16)));
    *(uint4*)&v[0] = *(const uint4*)src;
    *(uint4*)&v[8] = *(const uint4*)(src + 8);
#pragma unroll
    for (int j = 0; j < 16; ++j) tile[r][cg + j] = v[j];
    __syncthreads();
    u16 u[16] __attribute__((aligned(16)));
#pragma unroll
    for (int j = 0; j < 16; ++j) u[j] = tile[cg + j][r];
    u16* dst = Vt + ((size_t)b * DM + dmT * 64 + r) * SEQ + posT * 64 + cg;
    *(uint4*)&dst[0] = *(uint4*)&u[0];
    *(uint4*)&dst[8] = *(uint4*)&u[8];
  } else {  // K gather: Kc[b][p][:] = Kin[b][idx[p]][:], 512 blocks x 8 rows
    const int kb = bid - 1024;          // 0..511
    const int b = kb >> 8, rg = kb & 255;
    const int r = rg * 8 + (t >> 5);
    const int srow = idx[b * SEQ + r];
    const int co = (t & 31) * 4;        // uint4 index within the 2KB row
    const uint4* src = (const uint4*)(Kin + ((size_t)b * SEQ + srow) * DM);
    uint4* dst = (uint4*)(Kc + ((size_t)b * SEQ + r) * DM);
#pragma unroll
    for (int j = 0; j < 4; ++j) dst[co + j] = src[co + j];
  }
}

// ---------------------------------------------------------------------------
// GEMM (r7-proven 2-phase, 128x128, BK=64, double-buffered, T2-swizzled).
// A_F32: A is f32, reg-staged with fused convert (replaces the conv3 pass).
// Else: A bf16 via global_load_lds with inverse-swizzled source (rule #21).
// ---------------------------------------------------------------------------
template <int A_F32, int OUT_F32>
__device__ __forceinline__ void gemm128_body(
    const void* __restrict__ Av, const u16* __restrict__ Bt, void* __restrict__ Cv,
    int M, int N, int K, int bx, int by) {
  __shared__ u16 As[2][128 * 64];
  __shared__ u16 Bs[2][128 * 64];
  const int m0 = by * 128, n0 = bx * 128;
  const int t = threadIdx.x, w = t >> 6, l = t & 63;
  const int wr = w >> 1, wc = w & 1;
  const int frow = l & 15, fk8 = (l >> 4) * 8;
  const u16* Ab = (const u16*)Av;
  const float* Af = (const float*)Av;
  f32x4 acc[4][4] = {};

  // g2l16 staging geometry (r7-proven): chunk i -> LDS bytes T, source
  // (row, col) with inverse swizzle so lds_sw reads land correctly.
  int srow[4], scb[4];
#pragma unroll
  for (int i = 0; i < 4; ++i) {
    const int T = (i * 4 + w) * 1024 + l * 16;
    srow[i] = T >> 7;
    scb[i] = (T & 127) ^ ((srow[i] & 7) << 4);
  }

  float4 av[8];

#define ISSUE_B(buf, k0)                                                       \
  do {                                                                         \
    _Pragma("unroll")                                                          \
    for (int i = 0; i < 4; ++i)                                                \
      async_g2l16((const char*)(Bt + (size_t)(n0 + srow[i]) * K + (k0)) + scb[i], \
                  (char*)Bs[buf] + (i * 4 + w) * 1024);                        \
  } while (0)

#define ISSUE_A16(buf, k0)                                                     \
  do {                                                                         \
    _Pragma("unroll")                                                          \
    for (int i = 0; i < 4; ++i)                                                \
      async_g2l16((const char*)(Ab + (size_t)(m0 + srow[i]) * K + (k0)) + scb[i], \
                  (char*)As[buf] + (i * 4 + w) * 1024);                        \
  } while (0)

#define ISSUE_A32(k0)                                                          \
  do {                                                                         \
    _Pragma("unroll")                                                          \
    for (int c = 0; c < 8; ++c) {                                              \
      const int idx_ = c * 256 + t;                                            \
      av[c] = *(const float4*)(Af + (size_t)(m0 + (idx_ >> 4)) * K + (k0) +    \
                               (idx_ & 15) * 4);                               \
    }                                                                          \
  } while (0)

#define WRITE_A32(buf)                                                         \
  do {                                                                         \
    _Pragma("unroll")                                                          \
    for (int c = 0; c < 8; ++c) {                                              \
      const int idx_ = c * 256 + t;                                            \
      const int row_ = idx_ >> 4, c4_ = idx_ & 15;                             \
      uint32_t u0 = __builtin_bit_cast(uint32_t, av[c].x) + 0x8000u;           \
      uint32_t u1 = __builtin_bit_cast(uint32_t, av[c].y) + 0x8000u;           \
      uint32_t u2 = __builtin_bit_cast(uint32_t, av[c].z) + 0x8000u;           \
      uint32_t u3 = __builtin_bit_cast(uint32_t, av[c].w) + 0x8000u;           \
      uint2 pk;                                                                \
      pk.x = (u1 & 0xFFFF0000u) | (u0 >> 16);                                  \
      pk.y = (u3 & 0xFFFF0000u) | (u2 >> 16);                                  \
      *(uint2*)((char*)As[buf] + row_ * 128 + ((c4_ * 8) ^ ((row_ & 7) << 4))) = pk; \
    }                                                                          \
  } while (0)

  const int nks = K >> 6;
  // prologue: stage tile 0
  if (A_F32) { ISSUE_A32(0); } else { ISSUE_A16(0, 0); }
  ISSUE_B(0, 0);
  if (A_F32) WRITE_A32(0);
  __syncthreads();

  int cur = 0;
  for (int ks = 0; ks < nks; ++ks) {
    const bool more = (ks + 1 < nks);
    if (more) {
      if (A_F32) { ISSUE_A32((ks + 1) * 64); } else { ISSUE_A16(cur ^ 1, (ks + 1) * 64); }
      ISSUE_B(cur ^ 1, (ks + 1) * 64);
    }
    __builtin_amdgcn_s_setprio(1);
#pragma unroll
    for (int kk = 0; kk < 2; ++kk) {
      short8 af[4], bf[4];
#pragma unroll
      for (int mi = 0; mi < 4; ++mi)
        af[mi] = lds_sw((const char*)As[cur], wr * 64 + mi * 16 + frow,
                        kk * 64 + fk8 * 2);
#pragma unroll
      for (int ni = 0; ni < 4; ++ni)
        bf[ni] = lds_sw((const char*)Bs[cur], wc * 64 + ni * 16 + frow,
                        kk * 64 + fk8 * 2);
#pragma unroll
      for (int mi = 0; mi < 4; ++mi)
#pragma unroll
        for (int ni = 0; ni < 4; ++ni)
          acc[mi][ni] = MFMA(af[mi], bf[ni], acc[mi][ni]);
    }
    __builtin_amdgcn_s_setprio(0);
    if (more && A_F32) WRITE_A32(cur ^ 1);   // buf^1 free: last read iter ks-1
    __syncthreads();
    cur ^= 1;
  }
#undef ISSUE_B
#undef ISSUE_A16
#undef ISSUE_A32
#undef WRITE_A32

  const int crb = (l >> 4) * 4;
  for (int mi = 0; mi < 4; ++mi)
    for (int ni = 0; ni < 4; ++ni)
#pragma unroll
      for (int r = 0; r < 4; ++r) {
        const int row = m0 + wr * 64 + mi * 16 + crb + r;
        const int col = n0 + wc * 64 + ni * 16 + frow;
        if (OUT_F32) ((float*)Cv)[(size_t)row * N + col] = acc[mi][ni][r];
        else         ((u16*)Cv)[(size_t)row * N + col] = f2bf(acc[mi][ni][r]);
      }
}

// XCD-aware bijective swizzle for 256-block (8x32) grids
__device__ __forceinline__ void swz256(int& bx, int& by) {
  const int lin = by * 8 + bx;
  const int s = (lin & 7) * 32 + (lin >> 3);
  bx = s & 7; by = s >> 3;
}

__global__ __launch_bounds__(256) void gemm_qkv(
    const float* __restrict__ query, const float* __restrict__ key_,
    const float* __restrict__ value, const u16* __restrict__ wt,
    u16* __restrict__ out) {
  const int z = blockIdx.z;
  const float* A = (z == 0) ? query : (z == 1) ? key_ : value;
  int bx = blockIdx.x, by = blockIdx.y;
  swz256(bx, by);
  gemm128_body<1, 0>(A, wt + (size_t)z * DM * DM,
                     out + (size_t)z * NB * SEQ * DM,
                     NB * SEQ, DM, DM, bx, by);
}

__global__ __launch_bounds__(256) void gemm_out(
    const u16* __restrict__ A, const u16* __restrict__ Bt, float* __restrict__ C) {
  int bx = blockIdx.x, by = blockIdx.y;
  swz256(bx, by);
  gemm128_body<0, 1>(A, Bt, C, NB * SEQ, DM, DM, bx, by);
}

// ---------------------------------------------------------------------------
// Flash attention v4 (unchanged from rounds 6-8).
// ---------------------------------------------------------------------------
__global__ __launch_bounds__(512) void attn(
    const u16* __restrict__ Q, const u16* __restrict__ Kc,
    const u16* __restrict__ Vtc, const int* __restrict__ nkv,
    u16* __restrict__ O) {
  __shared__ uint4 ldsv[65536 / 16];
  char* lds = (char*)ldsv;       // [0,24K) K x3 | [24K,48K) V x3 | [48K,64K) P x8

  const int bid = blockIdx.x;
  const int swz = (bid & 7) * 64 + (bid >> 3);   // 512 blocks, bijective
  const int qt = swz & 15, h = (swz >> 4) & 15, b = swz >> 8;
  const int t = threadIdx.x, w = t >> 6, l = t & 63;
  const int frow = l & 15, fk8 = (l >> 4) * 8, crb = (l >> 4) * 4;
  const size_t tok0 = (size_t)b * SEQ;
  const int q0 = qt * 128 + w * 16;
  const int hc = h * DKH;
  char* PW = lds + 49152 + w * 2048;

  const int nk = nkv[b];
  const int nt = (nk + 63) >> 6;

  const int T0 = w * 1024 + l * 16;
  const int r0 = T0 >> 7;
  const int c0 = (T0 & 127) ^ ((r0 & 7) << 4);
  const u16* Kg = Kc + tok0 * DM + hc;
  const u16* Vg = Vtc + ((size_t)b * DM + hc) * SEQ;

  short8 qf[2];
#pragma unroll
  for (int ks = 0; ks < 2; ++ks)
    qf[ks] = *(const short8*)(Q + (tok0 + q0 + frow) * DM + hc + ks * 32 + fk8);

  const short ONE = 0x3F80;
  const short8 ONES = {ONE, ONE, ONE, ONE, ONE, ONE, ONE, ONE};

  f32x4 o[4] = {};
  f32x4 ol = {};
  float negm[4] = {-8.f, -8.f, -8.f, -8.f};

  char* kb0 = lds;          char* kb1 = lds + 8192;   char* kb2 = lds + 16384;
  char* vb0 = lds + 24576;  char* vb1 = lds + 32768;  char* vb2 = lds + 40960;

#define STAGE(tile, kd, vd)                                                    \
  do {                                                                         \
    const int kv_ = (tile) * 64;                                               \
    async_g2l16((const char*)(Kg + (size_t)(kv_ + r0) * DM) + c0, (kd) + w * 1024); \
    async_g2l16((const char*)(Vg + (size_t)r0 * SEQ + kv_) + c0, (vd) + w * 1024);  \
  } while (0)

  if (nt > 0) STAGE(0, kb0, vb0);
  if (nt > 1) STAGE(1, kb1, vb1);

  for (int it = 0; it < nt; ++it) {
    if (it + 1 < nt) { asm volatile("s_waitcnt vmcnt(2)" ::: "memory"); }
    else             { asm volatile("s_waitcnt vmcnt(0)" ::: "memory"); }
    __builtin_amdgcn_s_barrier();
    __builtin_amdgcn_sched_barrier(0);
    if (it + 2 < nt) STAGE(it + 2, kb2, vb2);

    const int kv0 = it * 64;
    const char* Kt = kb0;
    const char* Vt = vb0;

    // ---- QK^T + scale + negm fold ----
    f32x4 s[4];
#pragma unroll
    for (int n = 0; n < 4; ++n) {
      short8 kf0 = lds_sw(Kt, n * 16 + frow, fk8 * 2);
      short8 kf1 = lds_sw(Kt, n * 16 + frow, 64 + fk8 * 2);
      f32x4 a = {};
      a = MFMA(qf[0], kf0, a);
      a = MFMA(qf[1], kf1, a);
      s[n] = a;
    }
#pragma unroll
    for (int n = 0; n < 4; ++n)
#pragma unroll
      for (int r = 0; r < 4; ++r)
        s[n][r] = __builtin_fmaf(s[n][r], SCL, negm[r]);

    // ---- last-tile pad kill ----
    if (it == nt - 1) {
#pragma unroll
      for (int n = 0; n < 4; ++n) {
        const bool valid = (kv0 + n * 16 + frow) < nk;
#pragma unroll
        for (int r = 0; r < 4; ++r)
          s[n][r] = valid ? s[n][r] : -1e30f;
      }
    }

    // ---- defer-max (THR=8) ----
    float lm = fmaxf(fmaxf(fmaxf(s[0][0], s[0][1]), fmaxf(s[0][2], s[0][3])),
                     fmaxf(fmaxf(s[1][0], s[1][1]), fmaxf(s[1][2], s[1][3])));
    lm = fmaxf(lm, fmaxf(fmaxf(s[2][0], s[2][1]), fmaxf(s[2][2], s[2][3])));
    lm = fmaxf(lm, fmaxf(fmaxf(s[3][0], s[3][1]), fmaxf(s[3][2], s[3][3])));
    if (__any(lm > 8.0f)) {
#pragma unroll
      for (int r = 0; r < 4; ++r) {
        float mx = fmaxf(fmaxf(s[0][r], s[1][r]), fmaxf(s[2][r], s[3][r]));
        mx = fmaxf(mx, __shfl_xor(mx, 1));
        mx = fmaxf(mx, __shfl_xor(mx, 2));
        mx = fmaxf(mx, __shfl_xor(mx, 4));
        mx = fmaxf(mx, __shfl_xor(mx, 8));
        const float d = fmaxf(mx, 0.f);
        const float al = exp2f(-d);
        negm[r] -= d;
        ol[r] *= al;
#pragma unroll
        for (int dd = 0; dd < 4; ++dd) o[dd][r] *= al;
#pragma unroll
        for (int n = 0; n < 4; ++n) s[n][r] -= d;
      }
    }

    // ---- exp + truncated bf16 P write (swizzled) ----
#pragma unroll
    for (int n = 0; n < 4; ++n)
#pragma unroll
      for (int r = 0; r < 4; ++r) {
        const float p = exp2f(s[n][r]);
        *(u16*)(PW + (crb + r) * 128 +
                ((n * 32 + frow * 2) ^ (((crb + r) & 7) << 4))) =
            (u16)(__builtin_bit_cast(uint32_t, p) >> 16);
      }
    asm volatile("s_waitcnt lgkmcnt(0)" ::: "memory");
    __builtin_amdgcn_sched_barrier(0);

    // ---- PV + row-sum via ones-MFMA ----
    short8 pa0 = lds_sw(PW, frow, fk8 * 2);
    short8 pa1 = lds_sw(PW, frow, 64 + fk8 * 2);
    ol = MFMA(pa1, ONES, MFMA(pa0, ONES, ol));
#pragma unroll
    for (int d = 0; d < 4; ++d) {
      short8 vf0 = lds_sw(Vt, d * 16 + frow, fk8 * 2);
      short8 vf1 = lds_sw(Vt, d * 16 + frow, 64 + fk8 * 2);
      o[d] = MFMA(pa1, vf1, MFMA(pa0, vf0, o[d]));
    }

    // rotate buffers
    char* tk = kb0; kb0 = kb1; kb1 = kb2; kb2 = tk;
    char* tv = vb0; vb0 = vb1; vb1 = vb2; vb2 = tv;
  }
#undef STAGE

  // ---- epilogue ----
#pragma unroll
  for (int r = 0; r < 4; ++r) {
    const float den = ol[r];
    const float inv = den > 0.f ? 1.f / den : 0.f;
#pragma unroll
    for (int d = 0; d < 4; ++d)
      O[(tok0 + q0 + crb + r) * DM + hc + d * 16 + frow] = f2bf(o[d][r] * inv);
  }
}

// ---------------------------------------------------------------------------
extern "C" void kernel_launch(void* const* d_in, const int* in_sizes, int n_in,
                              void* d_out, int out_size, void* d_ws, size_t ws_size,
                              hipStream_t stream) {
  const float* query = (const float*)d_in[0];
  const float* key_  = (const float*)d_in[1];
  const float* value = (const float*)d_in[2];
  const int* mask    = (const int*)d_in[3];
  const float* wq = (const float*)d_in[4];
  const float* wk = (const float*)d_in[5];
  const float* wv = (const float*)d_in[6];
  const float* wo = (const float*)d_in[7];
  float* out = (float*)d_out;
  char* ws = (char*)d_ws;

  // ws layout (bytes):
  // [0,6M)    Wt_QKV (bf16, transposed)   [6M,8M)  Wt_O
  // [8M,16M)  Vtc   [16M,24M) attn_o   [24M,32M) Kc
  // [32M,56M) Q|K|V projections (bf16)
  // [56M,+16K) idx  [+16K,+8) nkv   (disjoint; r4 lesson)
  u16* wt_qkv = (u16*)(ws);
  u16* wt_o   = (u16*)(ws + (6u << 20));
  u16* vtc    = (u16*)(ws + (8u << 20));
  u16* attn_o = (u16*)(ws + (16u << 20));
  u16* kc     = (u16*)(ws + (24u << 20));
  u16* qkv    = (u16*)(ws + (32u << 20));
  int* idx    = (int*)(ws + (56u << 20));
  int* nkv    = (int*)(ws + (56u << 20) + 16384);

  prep<<<dim3(1026), 256, 0, stream>>>(
      mask, wq, wk, wv, wo, wt_qkv, wt_o, idx, nkv);

  gemm_qkv<<<dim3(DM / 128, (NB * SEQ) / 128, 3), 256, 0, stream>>>(
      query, key_, value, wt_qkv, qkv);

  kvprep<<<dim3(1536), 256, 0, stream>>>(
      qkv + (size_t)NB * SEQ * DM, qkv + (size_t)2 * NB * SEQ * DM, idx, kc, vtc);

  attn<<<dim3(NB * NH * (SEQ / 128)), 512, 0, stream>>>(
      qkv, kc, vtc, nkv, attn_o);

  gemm_out<<<dim3(DM / 128, (NB * SEQ) / 128), 256, 0, stream>>>(
      attn_o, wt_o, out);
}